// Round 9
// baseline (278.017 us; speedup 1.0000x reference)
//
#include <hip/hip_runtime.h>
#include <hip/hip_bf16.h>

// Problem: B=1024, S=64, E=256, H=512, V=128, C=32
#define BB 1024
#define SS 64
#define EE 256
#define HH 512
#define VV 128
#define CC 32

typedef _Float16 f16;
typedef _Float16 f16x4 __attribute__((ext_vector_type(4)));
typedef _Float16 f16x8 __attribute__((ext_vector_type(8)));
typedef float    f32x4 __attribute__((ext_vector_type(4)));

// ---------------------------------------------------------------------------
// ONE prep launch:
//   blocks 0..127   : P[v][h] = emb[v,:] . W_ih[h,:] + b_ih[h] + b_hh[h]
//   blocks 128..223 : f32->f16 tables  Whf = W_hh, W1f = W1, W2f = W2
// ---------------------------------------------------------------------------
#define CVT_TOT4   (65536 + 65536 + 4096)   // float4 units: W_hh, W1, W2
#define CVT_STRIDE (96 * 256)

__global__ __launch_bounds__(256) void prep_kernel(
    const float* __restrict__ emb, const float* __restrict__ W_ih,
    const float* __restrict__ b_ih, const float* __restrict__ b_hh,
    const float* __restrict__ W_hh, const float* __restrict__ W1,
    const float* __restrict__ W2,
    f16* __restrict__ P, f16* __restrict__ Whf,
    f16* __restrict__ W1f, f16* __restrict__ W2f)
{
    if (blockIdx.x < VV) {
        __shared__ float er[EE];
        const int v = blockIdx.x;
        for (int i = threadIdx.x; i < EE; i += 256) er[i] = emb[(size_t)v * EE + i];
        __syncthreads();
        for (int h = threadIdx.x; h < HH; h += 256) {
            const float4* wr = (const float4*)(W_ih + (size_t)h * EE);
            float s = 0.f;
            #pragma unroll 4
            for (int e4 = 0; e4 < EE / 4; ++e4) {
                float4 w = wr[e4];
                const float* e = er + e4 * 4;
                s += w.x * e[0] + w.y * e[1] + w.z * e[2] + w.w * e[3];
            }
            P[(size_t)v * HH + h] = (f16)(s + b_ih[h] + b_hh[h]);
        }
    } else {
        for (int i = (blockIdx.x - VV) * 256 + threadIdx.x; i < CVT_TOT4;
             i += CVT_STRIDE) {
            const float* src; f16* dst; int j;
            if (i < 65536)       { src = W_hh; dst = Whf; j = i; }
            else if (i < 131072) { src = W1;   dst = W1f; j = i - 65536; }
            else                 { src = W2;   dst = W2f; j = i - 131072; }
            float4 x = ((const float4*)src)[j];
            f16x4 y;
            y[0] = (f16)x.x; y[1] = (f16)x.y; y[2] = (f16)x.z; y[3] = (f16)x.w;
            *(f16x4*)(dst + (size_t)j * 4) = y;
        }
    }
}

// ---------------------------------------------------------------------------
// RNN + fused MLP head. 64 blocks x 512 threads (8 waves). Block owns 16
// batch rows, all 512 h-cols. W_hh: k 0..383 in regs (bfr[4][12]=192) plus
// one extra fragment bfrX (t=3,ks=15); k 384..511 minus that fragment in
// LDS wlds (120 KB).
//
// ROUND-9 CHANGES (each counter-motivated):
//  1. xin LDS table REMOVED -> tok read from global x_in each step. The old
//     xin read (dword 64*lrow+st) hit ONE bank for all 16 rows = 16-way
//     conflict = the measured 3.57M SQ_LDS_BANK_CONFLICT (~870 cyc/step).
//  2. hbuf DOUBLE-BUFFERED (2x16x512, zero pad, 32 KB) with XOR swizzle
//     byte ^= (row&7)<<4 (<=2-way on all accesses) -> ONE barrier per step:
//     reads hit buf[st&1], writes hit buf[(st+1)&1]; the end-of-step barrier
//     orders both. Epilogue of one wave now overlaps MFMA of another.
//  3. last -> global store in epilogue (frees 8 regs for bfrX/tok); tail
//     re-stages it from L2.
// LDS total: 32,768 + 122,880 = 155,648 B < 160 KB.
//
// REGISTER STRATEGY (proven r7/r8): the 49-operand asm forces all W
// fragments simultaneously live -> allocator abandons its 128-reg plan,
// overflow lives in AGPRs (unified file), zero scratch.
// MFMA operands SWAPPED: D = W_tile * h^T.
//   lane(lrow,quad), reg r -> h_next[batch=lrow][col = n0w + 16t + 4quad + r]
// ---------------------------------------------------------------------------
#define KSREG 12           // k-steps (of 32) held in registers
#define KSLDS 4            // k-steps in LDS (minus the t=3,ks=3 fragment)

#define KB(t,k) "v"(bfr[t][k])
#define KBT(t)  KB(t,0), KB(t,1), KB(t,2), KB(t,3), KB(t,4), KB(t,5), \
                KB(t,6), KB(t,7), KB(t,8), KB(t,9), KB(t,10), KB(t,11)

__global__
__attribute__((amdgpu_flat_work_group_size(512, 512)))
__attribute__((amdgpu_waves_per_eu(2, 2)))
void rnn_fused(
    const int* __restrict__ x_in, const int* __restrict__ x_lens,
    const f16* __restrict__ Whf, const f16* __restrict__ P,
    const f16* __restrict__ W1f, const float* __restrict__ b1,
    const f16* __restrict__ W2f, const float* __restrict__ b2,
    f16* __restrict__ last, float* __restrict__ out)
{
    __shared__ __align__(16) f16 hbuf[2 * 16 * 512];     // 32 KB, swizzled
    __shared__ __align__(16) f16 wlds[61440];            // 120 KB W fragments

    char* hb = (char*)hbuf;
    char* wl = (char*)wlds;

    const int tid  = threadIdx.x;
    const int r0   = blockIdx.x * 16;
    const int wave = tid >> 6;       // 0..7 -> cols [64w, 64w+64)
    const int lane = tid & 63;
    const int lrow = lane & 15;      // batch row (B-operand n / C col)
    const int quad = lane >> 4;
    const int n0w  = wave * 64;

    // swizzle constants: stored byte = linear ^ ((row&7)<<4)
    const int sw45 = (lrow & 3) << 4;
    const int sw6  = (lrow & 4) << 4;
    const int swf  = sw45 | sw6;
    // a-read base: linear = lrow*1024 + 64*ks + 16*quad (+sel); bits4-5 XORed in
    const int abase = (lrow << 10) + ((quad << 4) ^ sw45);
    // h-write base: linear = lrow*1024 + 2*n0w + 32*t + 8*quad (+sel)
    const int wbase = (lrow << 10) + (n0w << 1) + (quad << 3);

    // ---- one-time: Whf -> register fragments + LDS fragments ----
    // frag[k][n] = W_hh[n][k]; lane holds n = lrow(+16t+64w), k = 32ks+8quad+j
    f16x8 bfr[4][KSREG];
    f16x8 bfrX;                      // (t=3, ks=KSREG+3) kept in regs
    #pragma unroll
    for (int t = 0; t < 4; ++t) {
        const f16* wr = Whf + (size_t)(n0w + 16 * t + lrow) * HH + quad * 8;
        #pragma unroll
        for (int ks = 0; ks < KSREG; ++ks)
            bfr[t][ks] = *(const f16x8*)(wr + ks * 32);
        #pragma unroll
        for (int ks = 0; ks < KSLDS; ++ks) {
            f16x8 v = *(const f16x8*)(wr + (KSREG + ks) * 32);
            if (t == 3 && ks == KSLDS - 1) bfrX = v;
            else *(f16x8*)(wl + (((wave * 15 + t * 4 + ks) << 10) + (lane << 4))) = v;
        }
    }

    const int mylen = x_lens[r0 + lrow];
    const int xrow  = (r0 + lrow) * SS;
    const f16* pbase = P + n0w + quad * 4;
    f16* lastg = last + (size_t)(r0 + lrow) * HH + n0w + quad * 4;

    __syncthreads();   // wlds visible before first use (st=1)

    for (int st = 0; st < SS; ++st) {
        const int selr = (st & 1) << 14;
        const int selw = ((st + 1) & 1) << 14;

        // token for THIS step: global L1 (block slice = 4 KB), issued early
        const int tok = x_in[xrow + st];

        // force all 49 W fragments simultaneously resident (see header)
        asm volatile("" :: KBT(0), KBT(1), KBT(2), KBT(3), "v"(bfrX));

        // ---- MFMA: D = W_tile * h^T, 64 cols/wave x 16 rows, K = 512 ----
        f32x4 acc0 = {0,0,0,0}, acc1 = {0,0,0,0}, acc2 = {0,0,0,0}, acc3 = {0,0,0,0};
        if (st) {   // h_0 = 0 -> skip matmul at step 0
            const int ab = abase + selr;
            #pragma unroll
            for (int ks = 0; ks < KSREG; ++ks) {
                f16x8 a = *(const f16x8*)(hb + ((ab + (ks << 6)) ^ sw6));
                acc0 = __builtin_amdgcn_mfma_f32_16x16x32_f16(bfr[0][ks], a, acc0, 0, 0, 0);
                acc1 = __builtin_amdgcn_mfma_f32_16x16x32_f16(bfr[1][ks], a, acc1, 0, 0, 0);
                acc2 = __builtin_amdgcn_mfma_f32_16x16x32_f16(bfr[2][ks], a, acc2, 0, 0, 0);
                acc3 = __builtin_amdgcn_mfma_f32_16x16x32_f16(bfr[3][ks], a, acc3, 0, 0, 0);
            }
            #pragma unroll
            for (int ks = 0; ks < KSLDS; ++ks) {
                f16x8 a  = *(const f16x8*)(hb + ((ab + ((KSREG + ks) << 6)) ^ sw6));
                f16x8 b0 = *(const f16x8*)(wl + (((wave * 15 +  0 + ks) << 10) + (lane << 4)));
                f16x8 b1v = *(const f16x8*)(wl + (((wave * 15 +  4 + ks) << 10) + (lane << 4)));
                f16x8 b2v = *(const f16x8*)(wl + (((wave * 15 +  8 + ks) << 10) + (lane << 4)));
                f16x8 b3v = (ks == KSLDS - 1) ? bfrX
                          : *(const f16x8*)(wl + (((wave * 15 + 12 + ks) << 10) + (lane << 4)));
                acc0 = __builtin_amdgcn_mfma_f32_16x16x32_f16(b0,  a, acc0, 0, 0, 0);
                acc1 = __builtin_amdgcn_mfma_f32_16x16x32_f16(b1v, a, acc1, 0, 0, 0);
                acc2 = __builtin_amdgcn_mfma_f32_16x16x32_f16(b2v, a, acc2, 0, 0, 0);
                acc3 = __builtin_amdgcn_mfma_f32_16x16x32_f16(b3v, a, acc3, 0, 0, 0);
            }
        }

        // P addend: issued post-MFMA; other waves' MFMA phases cover latency
        const f16* pb = pbase + (size_t)tok * HH;
        f16x4 pv0 = *(const f16x4*)(pb);
        f16x4 pv1 = *(const f16x4*)(pb + 16);
        f16x4 pv2 = *(const f16x4*)(pb + 32);
        f16x4 pv3 = *(const f16x4*)(pb + 48);

        // ---- epilogue: h_{st+1}[lrow][n0w+16t+4q+r] = tanh(acc{t}[r] + P)
        // writes go to buf[(st+1)&1]; reads above hit buf[st&1] -> no race,
        // single end-of-step barrier orders everything.
        const int wb = wbase + selw;
        const bool wr_last = (mylen == st + 1);
        #pragma unroll
        for (int t = 0; t < 4; ++t) {
            const f32x4 acc = (t == 0) ? acc0 : (t == 1) ? acc1 : (t == 2) ? acc2 : acc3;
            const f16x4 pv  = (t == 0) ? pv0  : (t == 1) ? pv1  : (t == 2) ? pv2  : pv3;
            f16x4 hv;
            #pragma unroll
            for (int r = 0; r < 4; ++r) {
                float z = acc[r] + (float)pv[r];
                // tanh(z) = 1 - 2/(e^{2z}+1); exp saturation is correct
                float e = __expf(2.f * z);
                hv[r] = (f16)(1.f - 2.f / (e + 1.f));
            }
            *(f16x4*)(hb + ((wb + (t << 5)) ^ swf)) = hv;
            if (wr_last) *(f16x4*)(lastg + 16 * t) = hv;
        }

        __syncthreads();   // the ONE barrier per step
    }

    // ======================= fused MLP head =======================
    // stage last (global, L2-hot) -> buf0, swizzled
    for (int i = tid; i < 1024; i += 512) {
        const int row = i >> 6, c = i & 63;
        const int ofs = (((row << 10) + (c << 4)) ^ ((row & 7) << 4));
        *(f16x8*)(hb + ofs) =
            *(const f16x8*)(last + (size_t)(r0 + row) * HH + c * 8);
    }
    __syncthreads();

    // mlp1: hidden = relu(last @ W1^T + b1); A from buf0, B = W1f (L2)
    {
        f32x4 acc0 = {0,0,0,0}, acc1 = {0,0,0,0}, acc2 = {0,0,0,0}, acc3 = {0,0,0,0};
        #pragma unroll 4
        for (int ks = 0; ks < 16; ++ks) {
            f16x8 a = *(const f16x8*)(hb + ((abase + (ks << 6)) ^ sw6));
            const f16* w1r = W1f + (size_t)(n0w + lrow) * HH + ks * 32 + quad * 8;
            f16x8 b0 = *(const f16x8*)(w1r);
            f16x8 b1v = *(const f16x8*)(w1r + 16 * HH);
            f16x8 b2v = *(const f16x8*)(w1r + 32 * HH);
            f16x8 b3v = *(const f16x8*)(w1r + 48 * HH);
            acc0 = __builtin_amdgcn_mfma_f32_16x16x32_f16(b0,  a, acc0, 0, 0, 0);
            acc1 = __builtin_amdgcn_mfma_f32_16x16x32_f16(b1v, a, acc1, 0, 0, 0);
            acc2 = __builtin_amdgcn_mfma_f32_16x16x32_f16(b2v, a, acc2, 0, 0, 0);
            acc3 = __builtin_amdgcn_mfma_f32_16x16x32_f16(b3v, a, acc3, 0, 0, 0);
        }
        const int wb = wbase + 16384;      // hidden -> buf1
        #pragma unroll
        for (int t = 0; t < 4; ++t) {
            const f32x4 acc = (t == 0) ? acc0 : (t == 1) ? acc1 : (t == 2) ? acc2 : acc3;
            const float4 bv = *(const float4*)(b1 + n0w + 16 * t + quad * 4);
            const float  bb[4] = {bv.x, bv.y, bv.z, bv.w};
            f16x4 hv;
            #pragma unroll
            for (int r = 0; r < 4; ++r)
                hv[r] = (f16)fmaxf(acc[r] + bb[r], 0.f);
            *(f16x4*)(hb + ((wb + (t << 5)) ^ swf)) = hv;
        }
    }
    __syncthreads();

    // mlp2: logits = hidden @ W2^T + b2 (16 x 32, K=512); waves 0..1
    if (wave < 2) {
        f32x4 acc = {0,0,0,0};
        #pragma unroll 4
        for (int ks = 0; ks < 16; ++ks) {
            f16x8 a = *(const f16x8*)(hb + ((abase + 16384 + (ks << 6)) ^ sw6));
            f16x8 b = *(const f16x8*)(W2f + (size_t)(wave * 16 + lrow) * HH
                                      + ks * 32 + quad * 8);
            acc = __builtin_amdgcn_mfma_f32_16x16x32_f16(b, a, acc, 0, 0, 0);
        }
        const float4 bv = *(const float4*)(b2 + wave * 16 + quad * 4);
        float4 o;
        o.x = acc[0] + bv.x; o.y = acc[1] + bv.y;
        o.z = acc[2] + bv.z; o.w = acc[3] + bv.w;
        *(float4*)(out + (size_t)(r0 + lrow) * CC + wave * 16 + quad * 4) = o;
    }
}

// ---------------------------------------------------------------------------
extern "C" void kernel_launch(void* const* d_in, const int* in_sizes, int n_in,
                              void* d_out, int out_size, void* d_ws, size_t ws_size,
                              hipStream_t stream)
{
    const int*   x_in   = (const int*)d_in[0];
    const int*   x_lens = (const int*)d_in[1];
    const float* emb    = (const float*)d_in[2];
    const float* W_ih   = (const float*)d_in[3];
    const float* b_ih   = (const float*)d_in[4];
    const float* W_hh   = (const float*)d_in[5];
    const float* b_hh   = (const float*)d_in[6];
    const float* W1     = (const float*)d_in[7];
    const float* b1     = (const float*)d_in[8];
    const float* W2     = (const float*)d_in[9];
    const float* b2     = (const float*)d_in[10];
    float* out = (float*)d_out;

    // workspace carve (re-poisoned every launch; all tables rebuilt by prep)
    char* ws = (char*)d_ws;
    f16* P    = (f16*)ws;                               // 128 KiB
    f16* Whf  = (f16*)(ws + (128 << 10));               // 512 KiB
    f16* W1f  = (f16*)(ws + (640 << 10));               // 512 KiB
    f16* W2f  = (f16*)(ws + (1152 << 10));              //  32 KiB
    f16* last = (f16*)(ws + (1184 << 10));              //   1 MiB

    hipLaunchKernelGGL(prep_kernel, dim3(VV + 96), dim3(256), 0, stream,
                       emb, W_ih, b_ih, b_hh, W_hh, W1, W2, P, Whf, W1f, W2f);
    hipLaunchKernelGGL(rnn_fused, dim3(BB / 16), dim3(512), 0, stream,
                       x_in, x_lens, Whf, P, W1f, b1, W2f, b2, last, out);
}

// Round 10
// 243.897 us; speedup vs baseline: 1.1399x; 1.1399x over previous
//
#include <hip/hip_runtime.h>
#include <hip/hip_bf16.h>

// Problem: B=1024, S=64, E=256, H=512, V=128, C=32
#define BB 1024
#define SS 64
#define EE 256
#define HH 512
#define VV 128
#define CC 32

typedef _Float16 f16;
typedef _Float16 f16x4 __attribute__((ext_vector_type(4)));
typedef _Float16 f16x8 __attribute__((ext_vector_type(8)));
typedef float    f32x4 __attribute__((ext_vector_type(4)));

// ---------------------------------------------------------------------------
// ONE prep launch:
//   blocks 0..127   : P[v][h] = emb[v,:] . W_ih[h,:] + b_ih[h] + b_hh[h]
//   blocks 128..223 : f32->f16 tables  Whf = W_hh, W1f = W1, W2f = W2
// ---------------------------------------------------------------------------
#define CVT_TOT4   (65536 + 65536 + 4096)   // float4 units: W_hh, W1, W2
#define CVT_STRIDE (96 * 256)

__global__ __launch_bounds__(256) void prep_kernel(
    const float* __restrict__ emb, const float* __restrict__ W_ih,
    const float* __restrict__ b_ih, const float* __restrict__ b_hh,
    const float* __restrict__ W_hh, const float* __restrict__ W1,
    const float* __restrict__ W2,
    f16* __restrict__ P, f16* __restrict__ Whf,
    f16* __restrict__ W1f, f16* __restrict__ W2f)
{
    if (blockIdx.x < VV) {
        __shared__ float er[EE];
        const int v = blockIdx.x;
        for (int i = threadIdx.x; i < EE; i += 256) er[i] = emb[(size_t)v * EE + i];
        __syncthreads();
        for (int h = threadIdx.x; h < HH; h += 256) {
            const float4* wr = (const float4*)(W_ih + (size_t)h * EE);
            float s = 0.f;
            #pragma unroll 4
            for (int e4 = 0; e4 < EE / 4; ++e4) {
                float4 w = wr[e4];
                const float* e = er + e4 * 4;
                s += w.x * e[0] + w.y * e[1] + w.z * e[2] + w.w * e[3];
            }
            P[(size_t)v * HH + h] = (f16)(s + b_ih[h] + b_hh[h]);
        }
    } else {
        for (int i = (blockIdx.x - VV) * 256 + threadIdx.x; i < CVT_TOT4;
             i += CVT_STRIDE) {
            const float* src; f16* dst; int j;
            if (i < 65536)       { src = W_hh; dst = Whf; j = i; }
            else if (i < 131072) { src = W1;   dst = W1f; j = i - 65536; }
            else                 { src = W2;   dst = W2f; j = i - 131072; }
            float4 x = ((const float4*)src)[j];
            f16x4 y;
            y[0] = (f16)x.x; y[1] = (f16)x.y; y[2] = (f16)x.z; y[3] = (f16)x.w;
            *(f16x4*)(dst + (size_t)j * 4) = y;
        }
    }
}

// ---------------------------------------------------------------------------
// RNN + fused MLP head. 64 blocks x 512 threads (8 waves). Block owns 16
// batch rows, all 512 h-cols. W_hh: 49 of 64 fragments in regs, 15 in LDS.
//
// ROUND-10 (cycle-model-driven):
//  * tanh epilogue used IEEE fp32 division (v_div_scale/fmas/fixup ~12
//    VALU/elem x 16 elem/lane = ~1000 cyc/CU/step!) -> v_rcp_f32 + fma.
//  * all LDS addresses become base-reg + COMPILE-TIME immediate:
//    (ab + ks*64)^sw6 == ab + (ks^s6)*64 -> two bases abE/abO (even/odd ks);
//    step loop peeled (st=0, st=63) + 2x-unrolled so the double-buffer bit
//    is an immediate. Precomputed wadd[4] for epilogue writes. No per-step
//    address VALU, no `if(st)` branch.
//  * tok prefetched one step ahead (kills tok->P serial chain).
// Per-CU floor: 512 MFMA x 4.85cyc = 2483 cyc/step; we were at 7260.
//
// REGISTER STRATEGY (proven r7/r8): ONE inline-asm per unrolled body with
// all 49 W fragments as "v" inputs -> allocator can't meet a 128-reg plan,
// overflow lives in AGPRs (unified file), zero scratch (WRITE_SIZE 24MB->1MB).
// MFMA operands SWAPPED: D = W_tile * h^T.
//   lane(lrow,quad), reg r -> h_next[batch=lrow][col = n0w + 16t + 4quad + r]
// ---------------------------------------------------------------------------
#define KSREG 12           // k-steps (of 32) held in registers
#define KSLDS 4            // k-steps in LDS (minus the t=3,ks=3 fragment)

#define KB(t,k) "v"(bfr[t][k])
#define KBT(t)  KB(t,0), KB(t,1), KB(t,2), KB(t,3), KB(t,4), KB(t,5), \
                KB(t,6), KB(t,7), KB(t,8), KB(t,9), KB(t,10), KB(t,11)

// MFMA phase: reads h from buf with compile-time SEL (0 or 16384)
#define MFMA_PHASE(SEL)                                                         \
    _Pragma("unroll")                                                           \
    for (int ks = 0; ks < KSREG; ++ks) {                                        \
        f16x8 a = *(const f16x8*)(hb + ((ks & 1) ? abO : abE) + (SEL) + ks * 64);\
        acc0 = __builtin_amdgcn_mfma_f32_16x16x32_f16(bfr[0][ks], a, acc0, 0, 0, 0); \
        acc1 = __builtin_amdgcn_mfma_f32_16x16x32_f16(bfr[1][ks], a, acc1, 0, 0, 0); \
        acc2 = __builtin_amdgcn_mfma_f32_16x16x32_f16(bfr[2][ks], a, acc2, 0, 0, 0); \
        acc3 = __builtin_amdgcn_mfma_f32_16x16x32_f16(bfr[3][ks], a, acc3, 0, 0, 0); \
    }                                                                           \
    _Pragma("unroll")                                                           \
    for (int ks = 0; ks < KSLDS; ++ks) {                                        \
        f16x8 a = *(const f16x8*)(hb + (((KSREG + ks) & 1) ? abO : abE) + (SEL) \
                                  + (KSREG + ks) * 64);                         \
        f16x8 b0  = *(const f16x8*)(wl + wbse + ((0 * KSLDS + ks) << 10));      \
        f16x8 b1v = *(const f16x8*)(wl + wbse + ((1 * KSLDS + ks) << 10));      \
        f16x8 b2v = *(const f16x8*)(wl + wbse + ((2 * KSLDS + ks) << 10));      \
        f16x8 b3v = (ks == KSLDS - 1) ? bfrX                                    \
                  : *(const f16x8*)(wl + wbse + ((3 * KSLDS + ks) << 10));      \
        acc0 = __builtin_amdgcn_mfma_f32_16x16x32_f16(b0,  a, acc0, 0, 0, 0);   \
        acc1 = __builtin_amdgcn_mfma_f32_16x16x32_f16(b1v, a, acc1, 0, 0, 0);   \
        acc2 = __builtin_amdgcn_mfma_f32_16x16x32_f16(b2v, a, acc2, 0, 0, 0);   \
        acc3 = __builtin_amdgcn_mfma_f32_16x16x32_f16(b3v, a, acc3, 0, 0, 0);   \
    }

#define P_LOAD()                                                                \
    { const f16* pb = pbase + (size_t)tokc * HH;                                \
      pv0 = *(const f16x4*)(pb);                                                \
      pv1 = *(const f16x4*)(pb + 16);                                           \
      pv2 = *(const f16x4*)(pb + 32);                                           \
      pv3 = *(const f16x4*)(pb + 48); }

// epilogue: h = tanh(acc+P) via 1 - 2*rcp(e^{2z}+1); v_rcp, NOT ieee divide
#define EPILOGUE(SELW, TP1)                                                     \
    {                                                                           \
        const bool wr_last = (mylen == (TP1));                                  \
        _Pragma("unroll")                                                       \
        for (int t = 0; t < 4; ++t) {                                           \
            const f32x4 acc = (t==0)?acc0:(t==1)?acc1:(t==2)?acc2:acc3;         \
            const f16x4 pv  = (t==0)?pv0:(t==1)?pv1:(t==2)?pv2:pv3;             \
            f16x4 hv;                                                           \
            _Pragma("unroll")                                                   \
            for (int r = 0; r < 4; ++r) {                                       \
                float z = acc[r] + (float)pv[r];                                \
                float e = __expf(z + z);                                        \
                hv[r] = (f16)fmaf(-2.f, __builtin_amdgcn_rcpf(e + 1.f), 1.f);   \
            }                                                                   \
            *(f16x4*)(hb + wadd[t] + (SELW)) = hv;                              \
            if (wr_last) *(f16x4*)(lastg + 16 * t) = hv;                        \
        }                                                                       \
    }

__global__
__attribute__((amdgpu_flat_work_group_size(512, 512)))
__attribute__((amdgpu_waves_per_eu(2, 2)))
void rnn_fused(
    const int* __restrict__ x_in, const int* __restrict__ x_lens,
    const f16* __restrict__ Whf, const f16* __restrict__ P,
    const f16* __restrict__ W1f, const float* __restrict__ b1,
    const f16* __restrict__ W2f, const float* __restrict__ b2,
    f16* __restrict__ last, float* __restrict__ out)
{
    __shared__ __align__(16) f16 hbuf[2 * 16 * 512];     // 32 KB, swizzled
    __shared__ __align__(16) f16 wlds[61440];            // 120 KB W fragments

    char* hb = (char*)hbuf;
    char* wl = (char*)wlds;

    const int tid  = threadIdx.x;
    const int r0   = blockIdx.x * 16;
    const int wave = tid >> 6;       // 0..7 -> cols [64w, 64w+64)
    const int lane = tid & 63;
    const int lrow = lane & 15;      // batch row (B-operand n / C col)
    const int quad = lane >> 4;
    const int n0w  = wave * 64;

    // swizzle algebra: stored byte = linear ^ ((row&7)<<4).
    // a-read (row=lrow, chunk=quad+4ks): addr = ab0 + (ks^s6)*64
    //   = (even ks: abE, odd ks: abO) + ks*64  -> immediates only.
    const int s6   = (lrow >> 2) & 1;
    const int sw45 = (lrow & 3) << 4;
    const int swf  = (lrow & 7) << 4;
    const int ab0  = (lrow << 10) + ((quad << 4) ^ sw45);
    const int abE  = ab0 + s6 * 64;
    const int abO  = ab0 - s6 * 64;
    const int wbse = ((wave * 15) << 10) + (lane << 4);  // wlds read base
    int wadd[4];
    #pragma unroll
    for (int t = 0; t < 4; ++t)
        wadd[t] = ((lrow << 10) + (n0w << 1) + (quad << 3) + (t << 5)) ^ swf;

    // ---- one-time: Whf -> register fragments + LDS fragments ----
    f16x8 bfr[4][KSREG];
    f16x8 bfrX;                      // (t=3, ks=KSLDS-1) kept in regs
    #pragma unroll
    for (int t = 0; t < 4; ++t) {
        const f16* wr = Whf + (size_t)(n0w + 16 * t + lrow) * HH + quad * 8;
        #pragma unroll
        for (int ks = 0; ks < KSREG; ++ks)
            bfr[t][ks] = *(const f16x8*)(wr + ks * 32);
        #pragma unroll
        for (int ks = 0; ks < KSLDS; ++ks) {
            f16x8 v = *(const f16x8*)(wr + (KSREG + ks) * 32);
            if (t == 3 && ks == KSLDS - 1) bfrX = v;
            else *(f16x8*)(wl + (((wave * 15 + t * 4 + ks) << 10) + (lane << 4))) = v;
        }
    }

    const int mylen = x_lens[r0 + lrow];
    const int xrow  = (r0 + lrow) * SS;
    const f16* pbase = P + n0w + quad * 4;
    f16* lastg = last + (size_t)(r0 + lrow) * HH + n0w + quad * 4;

    __syncthreads();   // wlds visible before first use

    int tokc = x_in[xrow];          // token for st=0
    int tokn = x_in[xrow + 1];      // prefetch st=1

    // ---- st = 0 peel: h_1 = tanh(P[tok0]) -> buf1 ----
    {
        f32x4 acc0 = {0,0,0,0}, acc1 = {0,0,0,0}, acc2 = {0,0,0,0}, acc3 = {0,0,0,0};
        f16x4 pv0, pv1, pv2, pv3;
        P_LOAD();
        EPILOGUE(16384, 1);
        __syncthreads();
        tokc = tokn;
    }

    // ---- main: 31 x (odd st reads buf1->writes buf0; even reads buf0->buf1)
    for (int i = 0; i < 31; ++i) {
        const int st1 = 2 * i + 1;
        // force all 49 W fragments simultaneously resident (see header)
        asm volatile("" :: KBT(0), KBT(1), KBT(2), KBT(3), "v"(bfrX));

        {   // odd half
            tokn = x_in[xrow + st1 + 1];
            f32x4 acc0 = {0,0,0,0}, acc1 = {0,0,0,0}, acc2 = {0,0,0,0}, acc3 = {0,0,0,0};
            f16x4 pv0, pv1, pv2, pv3;
            MFMA_PHASE(16384);
            P_LOAD();
            EPILOGUE(0, st1 + 1);
            __syncthreads();
            tokc = tokn;
        }
        {   // even half (st2 = st1+1)
            tokn = x_in[xrow + st1 + 2];
            f32x4 acc0 = {0,0,0,0}, acc1 = {0,0,0,0}, acc2 = {0,0,0,0}, acc3 = {0,0,0,0};
            f16x4 pv0, pv1, pv2, pv3;
            MFMA_PHASE(0);
            P_LOAD();
            EPILOGUE(16384, st1 + 2);
            __syncthreads();
            tokc = tokn;
        }
    }

    // ---- st = 63 peel: reads buf1 ----
    {
        f32x4 acc0 = {0,0,0,0}, acc1 = {0,0,0,0}, acc2 = {0,0,0,0}, acc3 = {0,0,0,0};
        f16x4 pv0, pv1, pv2, pv3;
        MFMA_PHASE(16384);
        P_LOAD();
        EPILOGUE(0, 64);
        __syncthreads();
    }

    // ======================= fused MLP head =======================
    // stage last (global, L2-hot; drained by the barrier above) -> buf0
    for (int i = tid; i < 1024; i += 512) {
        const int row = i >> 6, c = i & 63;
        const int ofs = (((row << 10) + (c << 4)) ^ ((row & 7) << 4));
        *(f16x8*)(hb + ofs) =
            *(const f16x8*)(last + (size_t)(r0 + row) * HH + c * 8);
    }
    __syncthreads();

    // mlp1: hidden = relu(last @ W1^T + b1); A from buf0, B = W1f (L2)
    {
        f32x4 acc0 = {0,0,0,0}, acc1 = {0,0,0,0}, acc2 = {0,0,0,0}, acc3 = {0,0,0,0};
        #pragma unroll 4
        for (int ks = 0; ks < 16; ++ks) {
            f16x8 a = *(const f16x8*)(hb + ((ks & 1) ? abO : abE) + ks * 64);
            const f16* w1r = W1f + (size_t)(n0w + lrow) * HH + ks * 32 + quad * 8;
            f16x8 b0  = *(const f16x8*)(w1r);
            f16x8 b1v = *(const f16x8*)(w1r + 16 * HH);
            f16x8 b2v = *(const f16x8*)(w1r + 32 * HH);
            f16x8 b3v = *(const f16x8*)(w1r + 48 * HH);
            acc0 = __builtin_amdgcn_mfma_f32_16x16x32_f16(b0,  a, acc0, 0, 0, 0);
            acc1 = __builtin_amdgcn_mfma_f32_16x16x32_f16(b1v, a, acc1, 0, 0, 0);
            acc2 = __builtin_amdgcn_mfma_f32_16x16x32_f16(b2v, a, acc2, 0, 0, 0);
            acc3 = __builtin_amdgcn_mfma_f32_16x16x32_f16(b3v, a, acc3, 0, 0, 0);
        }
        __syncthreads();   // all waves done reading buf0 before hidden->buf1
        #pragma unroll
        for (int t = 0; t < 4; ++t) {
            const f32x4 acc = (t==0)?acc0:(t==1)?acc1:(t==2)?acc2:acc3;
            const float4 bv = *(const float4*)(b1 + n0w + 16 * t + quad * 4);
            const float  bb[4] = {bv.x, bv.y, bv.z, bv.w};
            f16x4 hv;
            #pragma unroll
            for (int r = 0; r < 4; ++r)
                hv[r] = (f16)fmaxf(acc[r] + bb[r], 0.f);
            *(f16x4*)(hb + wadd[t] + 16384) = hv;     // hidden -> buf1
        }
    }
    __syncthreads();

    // mlp2: logits = hidden @ W2^T + b2 (16 x 32, K=512); waves 0..1
    if (wave < 2) {
        f32x4 acc = {0,0,0,0};
        #pragma unroll 4
        for (int ks = 0; ks < 16; ++ks) {
            f16x8 a = *(const f16x8*)(hb + ((ks & 1) ? abO : abE) + 16384 + ks * 64);
            f16x8 b = *(const f16x8*)(W2f + (size_t)(wave * 16 + lrow) * HH
                                      + ks * 32 + quad * 8);
            acc = __builtin_amdgcn_mfma_f32_16x16x32_f16(b, a, acc, 0, 0, 0);
        }
        const float4 bv = *(const float4*)(b2 + wave * 16 + quad * 4);
        float4 o;
        o.x = acc[0] + bv.x; o.y = acc[1] + bv.y;
        o.z = acc[2] + bv.z; o.w = acc[3] + bv.w;
        *(float4*)(out + (size_t)(r0 + lrow) * CC + wave * 16 + quad * 4) = o;
    }
}

// ---------------------------------------------------------------------------
extern "C" void kernel_launch(void* const* d_in, const int* in_sizes, int n_in,
                              void* d_out, int out_size, void* d_ws, size_t ws_size,
                              hipStream_t stream)
{
    const int*   x_in   = (const int*)d_in[0];
    const int*   x_lens = (const int*)d_in[1];
    const float* emb    = (const float*)d_in[2];
    const float* W_ih   = (const float*)d_in[3];
    const float* b_ih   = (const float*)d_in[4];
    const float* W_hh   = (const float*)d_in[5];
    const float* b_hh   = (const float*)d_in[6];
    const float* W1     = (const float*)d_in[7];
    const float* b1     = (const float*)d_in[8];
    const float* W2     = (const float*)d_in[9];
    const float* b2     = (const float*)d_in[10];
    float* out = (float*)d_out;

    // workspace carve (re-poisoned every launch; all tables rebuilt by prep)
    char* ws = (char*)d_ws;
    f16* P    = (f16*)ws;                               // 128 KiB
    f16* Whf  = (f16*)(ws + (128 << 10));               // 512 KiB
    f16* W1f  = (f16*)(ws + (640 << 10));               // 512 KiB
    f16* W2f  = (f16*)(ws + (1152 << 10));              //  32 KiB
    f16* last = (f16*)(ws + (1184 << 10));              //   1 MiB

    hipLaunchKernelGGL(prep_kernel, dim3(VV + 96), dim3(256), 0, stream,
                       emb, W_ih, b_ih, b_hh, W_hh, W1, W2, P, Whf, W1f, W2f);
    hipLaunchKernelGGL(rnn_fused, dim3(BB / 16), dim3(512), 0, stream,
                       x_in, x_lens, Whf, P, W1f, b1, W2f, b2, last, out);
}